// Round 4
// baseline (121.239 us; speedup 1.0000x reference)
//
#include <hip/hip_runtime.h>

#define BB 2
#define NN 256
#define CC 256

// ---------------------------------------------------------------------------
// K1: fused q/k/v projections.  rows 0..511 = q (B*N), 512..1023 = k, 1024..1535 = v
// ---------------------------------------------------------------------------
__global__ __launch_bounds__(256) void proj_gemm(
    const float* __restrict__ q_tok, const float* __restrict__ k_tok, const float* __restrict__ v_tok,
    const float* __restrict__ Wq, const float* __restrict__ bq,
    const float* __restrict__ Wk, const float* __restrict__ bk,
    const float* __restrict__ Wv, const float* __restrict__ bv,
    float* __restrict__ out)
{
    const int row0 = blockIdx.x * 64;
    const int col0 = blockIdx.y * 64;
    const int seg  = row0 >> 9;
    const float* A    = seg == 0 ? q_tok : (seg == 1 ? k_tok : v_tok);
    const float* W    = seg == 0 ? Wq    : (seg == 1 ? Wk    : Wv);
    const float* bias = seg == 0 ? bq    : (seg == 1 ? bk    : bv);
    const int ar0 = row0 & 511;

    __shared__ float As[64][17];
    __shared__ float Bs[16][68];
    const int t  = threadIdx.x;
    const int tr = t >> 4, tc = t & 15;
    float acc[4][4] = {};

    const int sr  = t >> 2, sk4 = (t & 3) << 2;
    const int bkr = t >> 4, bj4 = (t & 15) << 2;

    for (int k0 = 0; k0 < 256; k0 += 16) {
        float4 a4 = *reinterpret_cast<const float4*>(&A[(ar0 + sr) * 256 + k0 + sk4]);
        float4 b4 = *reinterpret_cast<const float4*>(&W[(k0 + bkr) * 256 + col0 + bj4]);
        As[sr][sk4 + 0] = a4.x; As[sr][sk4 + 1] = a4.y; As[sr][sk4 + 2] = a4.z; As[sr][sk4 + 3] = a4.w;
        Bs[bkr][bj4 + 0] = b4.x; Bs[bkr][bj4 + 1] = b4.y; Bs[bkr][bj4 + 2] = b4.z; Bs[bkr][bj4 + 3] = b4.w;
        __syncthreads();
        #pragma unroll
        for (int k = 0; k < 16; ++k) {
            float a[4], bbv[4];
            #pragma unroll
            for (int i = 0; i < 4; ++i) a[i] = As[tr * 4 + i][k];
            #pragma unroll
            for (int j = 0; j < 4; ++j) bbv[j] = Bs[k][tc * 4 + j];
            #pragma unroll
            for (int i = 0; i < 4; ++i)
                #pragma unroll
                for (int j = 0; j < 4; ++j)
                    acc[i][j] = fmaf(a[i], bbv[j], acc[i][j]);
        }
        __syncthreads();
    }
    #pragma unroll
    for (int i = 0; i < 4; ++i) {
        const int r = row0 + tr * 4 + i;
        #pragma unroll
        for (int j = 0; j < 4; ++j) {
            const int cj = col0 + tc * 4 + j;
            out[r * 256 + cj] = acc[i][j] + bias[cj];
        }
    }
}

// ---------------------------------------------------------------------------
// K2: qW[bn][h][d] = sum_c qp[bn][h*64+c] * Wqk[d][h*64+c]
// ---------------------------------------------------------------------------
__global__ __launch_bounds__(256) void qw_gemm(
    const float* __restrict__ qp, const float* __restrict__ Wqk, float* __restrict__ qW)
{
    const int h    = blockIdx.z;
    const int row0 = blockIdx.x * 64;
    const int d0   = blockIdx.y * 64;
    __shared__ float As[64][17];
    __shared__ float Bs[16][68];
    const int t  = threadIdx.x;
    const int tr = t >> 4, tc = t & 15;
    float acc[4][4] = {};
    const int sr = t >> 2, sc4 = (t & 3) << 2;

    for (int k0 = 0; k0 < 64; k0 += 16) {
        float4 a4 = *reinterpret_cast<const float4*>(&qp[(row0 + sr) * 256 + h * 64 + k0 + sc4]);
        float4 b4 = *reinterpret_cast<const float4*>(&Wqk[(d0 + sr) * 256 + h * 64 + k0 + sc4]);
        As[sr][sc4 + 0] = a4.x; As[sr][sc4 + 1] = a4.y; As[sr][sc4 + 2] = a4.z; As[sr][sc4 + 3] = a4.w;
        Bs[sc4 + 0][sr] = b4.x; Bs[sc4 + 1][sr] = b4.y; Bs[sc4 + 2][sr] = b4.z; Bs[sc4 + 3][sr] = b4.w;
        __syncthreads();
        #pragma unroll
        for (int k = 0; k < 16; ++k) {
            float a[4], bbv[4];
            #pragma unroll
            for (int i = 0; i < 4; ++i) a[i] = As[tr * 4 + i][k];
            #pragma unroll
            for (int j = 0; j < 4; ++j) bbv[j] = Bs[k][tc * 4 + j];
            #pragma unroll
            for (int i = 0; i < 4; ++i)
                #pragma unroll
                for (int j = 0; j < 4; ++j)
                    acc[i][j] = fmaf(a[i], bbv[j], acc[i][j]);
        }
        __syncthreads();
    }
    #pragma unroll
    for (int i = 0; i < 4; ++i)
        #pragma unroll
        for (int j = 0; j < 4; ++j)
            qW[((row0 + tr * 4 + i) * 4 + h) * 256 + d0 + tc * 4 + j] = acc[i][j];
}

__device__ __forceinline__ float dot4acc(float4 e, float4 w, float s) {
    s = fmaf(e.x, w.x, s); s = fmaf(e.y, w.y, s);
    s = fmaf(e.z, w.z, s); s = fmaf(e.w, w.w, s);
    return s;
}

// ---------------------------------------------------------------------------
// S1: block (bn, ms) streams qk_emb rows [ms*64, ms*64+64), computes
// raw scores Sg[bh n][m] = (qW . e + q . k) * 0.125.  256 thr, 6KB LDS.
// ---------------------------------------------------------------------------
__global__ __launch_bounds__(256) void scores_kernel(
    const float* __restrict__ qk_emb, const float* __restrict__ qkvp,
    const float* __restrict__ qW, float* __restrict__ Sg)
{
    const int bn = blockIdx.x;
    const int ms = blockIdx.y;
    const int b  = bn >> 8, n = bn & 255;
    const int t  = threadIdx.x;
    const int w  = t >> 6, l = t & 63;
    __shared__ float qWs[4][256];
    __shared__ float qrow[256];
    __shared__ float S_lds[4][64];

    *reinterpret_cast<float4*>(&qWs[t >> 6][(t & 63) * 4]) =
        *reinterpret_cast<const float4*>(&qW[(size_t)bn * 1024 + t * 4]);
    qrow[t] = qkvp[bn * 256 + t];
    __syncthreads();

    const int lq = l & 15, lr = l >> 4;
    #pragma unroll
    for (int g = 0; g < 4; ++g) {
        const int mi = w * 16 + g * 4 + lr;
        const int m  = ms * 64 + mi;
        const float* er = qk_emb + (size_t)(bn * 256 + m) * 256 + lq * 4;
        const float4 e0 = *reinterpret_cast<const float4*>(er);
        const float4 e1 = *reinterpret_cast<const float4*>(er + 64);
        const float4 e2 = *reinterpret_cast<const float4*>(er + 128);
        const float4 e3 = *reinterpret_cast<const float4*>(er + 192);
        float a[4];
        #pragma unroll
        for (int h = 0; h < 4; ++h) {
            float s = 0.f;
            s = dot4acc(e0, *reinterpret_cast<const float4*>(&qWs[h][lq * 4]),       s);
            s = dot4acc(e1, *reinterpret_cast<const float4*>(&qWs[h][64 + lq * 4]),  s);
            s = dot4acc(e2, *reinterpret_cast<const float4*>(&qWs[h][128 + lq * 4]), s);
            s = dot4acc(e3, *reinterpret_cast<const float4*>(&qWs[h][192 + lq * 4]), s);
            a[h] = s;
        }
        #pragma unroll
        for (int h = 0; h < 4; ++h) {
            a[h] += __shfl_xor(a[h], 1);
            a[h] += __shfl_xor(a[h], 2);
            a[h] += __shfl_xor(a[h], 4);
            a[h] += __shfl_xor(a[h], 8);
        }
        if (lq == 0) {
            #pragma unroll
            for (int h = 0; h < 4; ++h) S_lds[h][mi] = a[h];
        }
    }
    __syncthreads();

    // one thread per (h, mi): add q.k, write raw score
    const int h2 = t >> 6, mi2 = t & 63, m2 = ms * 64 + mi2;
    const float* kr = qkvp + (size_t)(512 + b * 256 + m2) * 256 + h2 * 64;
    float dot = 0.f;
    #pragma unroll 8
    for (int c = 0; c < 64; ++c) dot = fmaf(qrow[h2 * 64 + c], kr[c], dot);
    Sg[(size_t)((b * 4 + h2) * 256 + n) * 256 + m2] = (S_lds[h2][mi2] + dot) * 0.125f;
}

// ---------------------------------------------------------------------------
// S1b: per (bn): wave h reduces its score row -> (max, 1/sumexp)
// ---------------------------------------------------------------------------
__global__ __launch_bounds__(256) void softmax_stats(
    const float* __restrict__ Sg, float* __restrict__ MS)
{
    const int bn = blockIdx.x;
    const int b = bn >> 8, n = bn & 255;
    const int t = threadIdx.x;
    const int h = t >> 6, l = t & 63;
    const float* row = Sg + (size_t)((b * 4 + h) * 256 + n) * 256;
    const float4 s4 = *reinterpret_cast<const float4*>(&row[l * 4]);
    float mx = fmaxf(fmaxf(s4.x, s4.y), fmaxf(s4.z, s4.w));
    #pragma unroll
    for (int mask = 32; mask >= 1; mask >>= 1) mx = fmaxf(mx, __shfl_xor(mx, mask));
    float e = __expf(s4.x - mx) + __expf(s4.y - mx) + __expf(s4.z - mx) + __expf(s4.w - mx);
    #pragma unroll
    for (int mask = 32; mask >= 1; mask >>= 1) e += __shfl_xor(e, mask);
    if (l == 0) {
        const int idx = ((b * 4 + h) * 256 + n) * 2;
        MS[idx] = mx;
        MS[idx + 1] = 1.f / e;
    }
}

// ---------------------------------------------------------------------------
// S2: block (bn, ms): attn = exp(S-mx)*inv (write to d_out), stream qv_emb
// chunk, accumulate A-partials Ag[bn][ms][h][d].  256 thr, 17KB LDS.
// ---------------------------------------------------------------------------
__global__ __launch_bounds__(256) void accum_kernel(
    const float* __restrict__ qv_emb, const float* __restrict__ Sg,
    const float* __restrict__ MS, float* __restrict__ attn_out,
    float* __restrict__ Ag)
{
    const int bn = blockIdx.x, ms = blockIdx.y;
    const int b = bn >> 8, n = bn & 255;
    const int t = threadIdx.x, w = t >> 6, l = t & 63;
    __shared__ float attn_lds[4][64];
    __shared__ float Apw[4][4][256];

    {
        const int h = t >> 6, mi = t & 63;
        const size_t off = (size_t)((b * 4 + h) * 256 + n) * 256 + ms * 64 + mi;
        const int sidx = ((b * 4 + h) * 256 + n) * 2;
        const float a = __expf(Sg[off] - MS[sidx]) * MS[sidx + 1];
        attn_lds[h][mi] = a;
        attn_out[off] = a;
    }
    __syncthreads();

    float4 acc[4];
    #pragma unroll
    for (int h = 0; h < 4; ++h) acc[h] = make_float4(0.f, 0.f, 0.f, 0.f);

    #pragma unroll
    for (int rr = 0; rr < 16; rr += 2) {
        const int mi0 = w * 16 + rr;
        const float4 e0 = *reinterpret_cast<const float4*>(
            &qv_emb[(size_t)(bn * 256 + ms * 64 + mi0) * 256 + l * 4]);
        const float4 e1 = *reinterpret_cast<const float4*>(
            &qv_emb[(size_t)(bn * 256 + ms * 64 + mi0 + 1) * 256 + l * 4]);
        #pragma unroll
        for (int h = 0; h < 4; ++h) {
            const float a0 = attn_lds[h][mi0];
            const float a1 = attn_lds[h][mi0 + 1];
            acc[h].x = fmaf(a0, e0.x, acc[h].x); acc[h].y = fmaf(a0, e0.y, acc[h].y);
            acc[h].z = fmaf(a0, e0.z, acc[h].z); acc[h].w = fmaf(a0, e0.w, acc[h].w);
            acc[h].x = fmaf(a1, e1.x, acc[h].x); acc[h].y = fmaf(a1, e1.y, acc[h].y);
            acc[h].z = fmaf(a1, e1.z, acc[h].z); acc[h].w = fmaf(a1, e1.w, acc[h].w);
        }
    }
    #pragma unroll
    for (int h = 0; h < 4; ++h)
        *reinterpret_cast<float4*>(&Apw[w][h][l * 4]) = acc[h];
    __syncthreads();

    #pragma unroll
    for (int i = 0; i < 4; ++i) {
        const int idx = t + i * 256, h = idx >> 8, d = idx & 255;
        Ag[((size_t)(bn * 4 + ms) * 4 + h) * 256 + d] =
            Apw[0][h][d] + Apw[1][h][d] + Apw[2][h][d] + Apw[3][h][d];
    }
}

// ---------------------------------------------------------------------------
// S3: per (bn): hidden = attn@v + (sum_ms Ag)@Wqv + bqv
// ---------------------------------------------------------------------------
__global__ __launch_bounds__(256) void final_kernel(
    const float* __restrict__ qkvp, const float* __restrict__ Wqv,
    const float* __restrict__ bqv, const float* __restrict__ attn,
    const float* __restrict__ Ag, float* __restrict__ hidden)
{
    const int bn = blockIdx.x;
    const int b = bn >> 8, n = bn & 255;
    const int t = threadIdx.x;
    __shared__ float attn_s[4][256];
    __shared__ float Afull[4][256];

    {
        const int h = t >> 6, m4 = (t & 63) * 4;
        *reinterpret_cast<float4*>(&attn_s[h][m4]) =
            *reinterpret_cast<const float4*>(&attn[(size_t)((b * 4 + h) * 256 + n) * 256 + m4]);
    }
    #pragma unroll
    for (int i = 0; i < 4; ++i) {
        const int idx = t + i * 256, h = idx >> 8, d = idx & 255;
        float s = 0.f;
        #pragma unroll
        for (int msi = 0; msi < 4; ++msi)
            s += Ag[((size_t)(bn * 4 + msi) * 4 + h) * 256 + d];
        Afull[h][d] = s;
    }
    __syncthreads();

    const int c = t, h = c >> 6;
    float hv = bqv[c];
    const float* vcol = qkvp + (size_t)(1024 + b * 256) * 256 + c;
    #pragma unroll 8
    for (int m = 0; m < 256; ++m) hv = fmaf(attn_s[h][m], vcol[m * 256], hv);
    const float* wcol = Wqv + c;
    #pragma unroll 8
    for (int d = 0; d < 256; ++d) hv = fmaf(Afull[h][d], wcol[d * 256], hv);
    hidden[(size_t)bn * 256 + c] = hv;
}

extern "C" void kernel_launch(void* const* d_in, const int* in_sizes, int n_in,
                              void* d_out, int out_size, void* d_ws, size_t ws_size,
                              hipStream_t stream) {
    (void)in_sizes; (void)n_in; (void)out_size; (void)ws_size;
    const float* q_tok  = (const float*)d_in[0];
    const float* k_tok  = (const float*)d_in[1];
    const float* v_tok  = (const float*)d_in[2];
    const float* qk_emb = (const float*)d_in[3];
    const float* qv_emb = (const float*)d_in[4];
    const float* Wq  = (const float*)d_in[5];   const float* bq  = (const float*)d_in[6];
    const float* Wk  = (const float*)d_in[7];   const float* bk  = (const float*)d_in[8];
    const float* Wv  = (const float*)d_in[9];   const float* bv  = (const float*)d_in[10];
    const float* Wqk = (const float*)d_in[11];  /* bqk softmax-invariant */
    const float* Wqv = (const float*)d_in[13];  const float* bqv = (const float*)d_in[14];

    float* ws   = (float*)d_ws;
    float* qkvp = ws;                      // 1536*256            = 393216
    float* qW   = ws + 393216;             // 512*1024            = 524288
    float* Sg   = ws + 917504;             // 2048*256            = 524288
    float* MS   = ws + 1441792;            // 2048*2              = 4096
    float* Ag   = ws + 1445888;            // 512*4*4*256         = 2097152

    float* hidden = (float*)d_out;
    float* attn   = (float*)d_out + BB * NN * CC;

    proj_gemm    <<<dim3(24, 4),   256, 0, stream>>>(q_tok, k_tok, v_tok, Wq, bq, Wk, bk, Wv, bv, qkvp);
    qw_gemm      <<<dim3(8, 4, 4), 256, 0, stream>>>(qkvp, Wqk, qW);
    scores_kernel<<<dim3(512, 4),  256, 0, stream>>>(qk_emb, qkvp, qW, Sg);
    softmax_stats<<<512,           256, 0, stream>>>(Sg, MS);
    accum_kernel <<<dim3(512, 4),  256, 0, stream>>>(qv_emb, Sg, MS, attn, Ag);
    final_kernel <<<512,           256, 0, stream>>>(qkvp, Wqv, bqv, attn, Ag, hidden);
}

// Round 5
// 109.342 us; speedup vs baseline: 1.1088x; 1.1088x over previous
//
#include <hip/hip_runtime.h>

#define BB 2
#define NN 256
#define CC 256

// ---------------------------------------------------------------------------
// K1: fused q/k/v projections.  rows 0..511 = q (B*N), 512..1023 = k, 1024..1535 = v
// ---------------------------------------------------------------------------
__global__ __launch_bounds__(256) void proj_gemm(
    const float* __restrict__ q_tok, const float* __restrict__ k_tok, const float* __restrict__ v_tok,
    const float* __restrict__ Wq, const float* __restrict__ bq,
    const float* __restrict__ Wk, const float* __restrict__ bk,
    const float* __restrict__ Wv, const float* __restrict__ bv,
    float* __restrict__ out)
{
    const int row0 = blockIdx.x * 64;
    const int col0 = blockIdx.y * 64;
    const int seg  = row0 >> 9;
    const float* A    = seg == 0 ? q_tok : (seg == 1 ? k_tok : v_tok);
    const float* W    = seg == 0 ? Wq    : (seg == 1 ? Wk    : Wv);
    const float* bias = seg == 0 ? bq    : (seg == 1 ? bk    : bv);
    const int ar0 = row0 & 511;

    __shared__ float As[64][17];
    __shared__ float Bs[16][68];
    const int t  = threadIdx.x;
    const int tr = t >> 4, tc = t & 15;
    float acc[4][4] = {};

    const int sr  = t >> 2, sk4 = (t & 3) << 2;
    const int bkr = t >> 4, bj4 = (t & 15) << 2;

    for (int k0 = 0; k0 < 256; k0 += 16) {
        float4 a4 = *reinterpret_cast<const float4*>(&A[(ar0 + sr) * 256 + k0 + sk4]);
        float4 b4 = *reinterpret_cast<const float4*>(&W[(k0 + bkr) * 256 + col0 + bj4]);
        As[sr][sk4 + 0] = a4.x; As[sr][sk4 + 1] = a4.y; As[sr][sk4 + 2] = a4.z; As[sr][sk4 + 3] = a4.w;
        Bs[bkr][bj4 + 0] = b4.x; Bs[bkr][bj4 + 1] = b4.y; Bs[bkr][bj4 + 2] = b4.z; Bs[bkr][bj4 + 3] = b4.w;
        __syncthreads();
        #pragma unroll
        for (int k = 0; k < 16; ++k) {
            float a[4], bbv[4];
            #pragma unroll
            for (int i = 0; i < 4; ++i) a[i] = As[tr * 4 + i][k];
            #pragma unroll
            for (int j = 0; j < 4; ++j) bbv[j] = Bs[k][tc * 4 + j];
            #pragma unroll
            for (int i = 0; i < 4; ++i)
                #pragma unroll
                for (int j = 0; j < 4; ++j)
                    acc[i][j] = fmaf(a[i], bbv[j], acc[i][j]);
        }
        __syncthreads();
    }
    #pragma unroll
    for (int i = 0; i < 4; ++i) {
        const int r = row0 + tr * 4 + i;
        #pragma unroll
        for (int j = 0; j < 4; ++j) {
            const int cj = col0 + tc * 4 + j;
            out[r * 256 + cj] = acc[i][j] + bias[cj];
        }
    }
}

// ---------------------------------------------------------------------------
// K2: qW[bn][h][d] = sum_c qp[bn][h*64+c] * Wqk[d][h*64+c]
// ---------------------------------------------------------------------------
__global__ __launch_bounds__(256) void qw_gemm(
    const float* __restrict__ qp, const float* __restrict__ Wqk, float* __restrict__ qW)
{
    const int h    = blockIdx.z;
    const int row0 = blockIdx.x * 64;
    const int d0   = blockIdx.y * 64;
    __shared__ float As[64][17];
    __shared__ float Bs[16][68];
    const int t  = threadIdx.x;
    const int tr = t >> 4, tc = t & 15;
    float acc[4][4] = {};
    const int sr = t >> 2, sc4 = (t & 3) << 2;

    for (int k0 = 0; k0 < 64; k0 += 16) {
        float4 a4 = *reinterpret_cast<const float4*>(&qp[(row0 + sr) * 256 + h * 64 + k0 + sc4]);
        float4 b4 = *reinterpret_cast<const float4*>(&Wqk[(d0 + sr) * 256 + h * 64 + k0 + sc4]);
        As[sr][sc4 + 0] = a4.x; As[sr][sc4 + 1] = a4.y; As[sr][sc4 + 2] = a4.z; As[sr][sc4 + 3] = a4.w;
        Bs[sc4 + 0][sr] = b4.x; Bs[sc4 + 1][sr] = b4.y; Bs[sc4 + 2][sr] = b4.z; Bs[sc4 + 3][sr] = b4.w;
        __syncthreads();
        #pragma unroll
        for (int k = 0; k < 16; ++k) {
            float a[4], bbv[4];
            #pragma unroll
            for (int i = 0; i < 4; ++i) a[i] = As[tr * 4 + i][k];
            #pragma unroll
            for (int j = 0; j < 4; ++j) bbv[j] = Bs[k][tc * 4 + j];
            #pragma unroll
            for (int i = 0; i < 4; ++i)
                #pragma unroll
                for (int j = 0; j < 4; ++j)
                    acc[i][j] = fmaf(a[i], bbv[j], acc[i][j]);
        }
        __syncthreads();
    }
    #pragma unroll
    for (int i = 0; i < 4; ++i)
        #pragma unroll
        for (int j = 0; j < 4; ++j)
            qW[((row0 + tr * 4 + i) * 4 + h) * 256 + d0 + tc * 4 + j] = acc[i][j];
}

// ---------------------------------------------------------------------------
// K2b: Sqk[((b*4+h)*256+n)*256+m] = sum_c q[b,n,h*64+c] * k[b,m,h*64+c]  (raw)
// ---------------------------------------------------------------------------
__global__ __launch_bounds__(256) void qk_gemm(
    const float* __restrict__ qkvp, float* __restrict__ Sqk)
{
    const int bh = blockIdx.z;
    const int b  = bh >> 2, h = bh & 3;
    const int n0 = blockIdx.x * 64;
    const int m0 = blockIdx.y * 64;
    __shared__ float As[64][17];
    __shared__ float Bs[16][68];
    const int t  = threadIdx.x;
    const int tr = t >> 4, tc = t & 15;
    float acc[4][4] = {};
    const int sr = t >> 2, sc4 = (t & 3) << 2;

    for (int k0 = 0; k0 < 64; k0 += 16) {
        float4 a4 = *reinterpret_cast<const float4*>(&qkvp[(size_t)(b * 256 + n0 + sr) * 256 + h * 64 + k0 + sc4]);
        float4 b4 = *reinterpret_cast<const float4*>(&qkvp[(size_t)(512 + b * 256 + m0 + sr) * 256 + h * 64 + k0 + sc4]);
        As[sr][sc4 + 0] = a4.x; As[sr][sc4 + 1] = a4.y; As[sr][sc4 + 2] = a4.z; As[sr][sc4 + 3] = a4.w;
        Bs[sc4 + 0][sr] = b4.x; Bs[sc4 + 1][sr] = b4.y; Bs[sc4 + 2][sr] = b4.z; Bs[sc4 + 3][sr] = b4.w;
        __syncthreads();
        #pragma unroll
        for (int k = 0; k < 16; ++k) {
            float a[4], bbv[4];
            #pragma unroll
            for (int i = 0; i < 4; ++i) a[i] = As[tr * 4 + i][k];
            #pragma unroll
            for (int j = 0; j < 4; ++j) bbv[j] = Bs[k][tc * 4 + j];
            #pragma unroll
            for (int i = 0; i < 4; ++i)
                #pragma unroll
                for (int j = 0; j < 4; ++j)
                    acc[i][j] = fmaf(a[i], bbv[j], acc[i][j]);
        }
        __syncthreads();
    }
    #pragma unroll
    for (int i = 0; i < 4; ++i)
        #pragma unroll
        for (int j = 0; j < 4; ++j)
            Sqk[(size_t)((b * 4 + h) * 256 + n0 + tr * 4 + i) * 256 + m0 + tc * 4 + j] = acc[i][j];
}

__device__ __forceinline__ float dot4acc(float4 e, float4 w, float s) {
    s = fmaf(e.x, w.x, s); s = fmaf(e.y, w.y, s);
    s = fmaf(e.z, w.z, s); s = fmaf(e.w, w.w, s);
    return s;
}

// ---------------------------------------------------------------------------
// S1: block (bn, ms in 0..7) streams 32 rows of qk_emb (32 KB) with 8
// independent float4 loads per thread upfront.  Sg = (pair + Sqk) * 0.125.
// Wave w owns rows [w*8, w*8+8); lane: lq=l&15 d-slice, lr=l>>4 row.
// ---------------------------------------------------------------------------
__global__ __launch_bounds__(256) void scores_kernel(
    const float* __restrict__ qk_emb, const float* __restrict__ qW,
    const float* __restrict__ Sqk, float* __restrict__ Sg)
{
    const int bn = blockIdx.x;
    const int ms = blockIdx.y;
    const int b  = bn >> 8, n = bn & 255;
    const int t  = threadIdx.x;
    const int w  = t >> 6, l = t & 63;
    const int lq = l & 15, lr = l >> 4;
    __shared__ float qWs[4][256];
    __shared__ float S_lds[4][32];

    *reinterpret_cast<float4*>(&qWs[t >> 6][(t & 63) * 4]) =
        *reinterpret_cast<const float4*>(&qW[(size_t)bn * 1024 + t * 4]);
    __syncthreads();

    // 8 independent loads: 2 row-groups x 4 quarter-pieces
    const float* r0 = qk_emb + (size_t)(bn * 256 + ms * 32 + w * 8 + lr) * 256 + lq * 4;
    const float* r1 = r0 + 4 * 256;
    const float4 e00 = *reinterpret_cast<const float4*>(r0);
    const float4 e01 = *reinterpret_cast<const float4*>(r0 + 64);
    const float4 e02 = *reinterpret_cast<const float4*>(r0 + 128);
    const float4 e03 = *reinterpret_cast<const float4*>(r0 + 192);
    const float4 e10 = *reinterpret_cast<const float4*>(r1);
    const float4 e11 = *reinterpret_cast<const float4*>(r1 + 64);
    const float4 e12 = *reinterpret_cast<const float4*>(r1 + 128);
    const float4 e13 = *reinterpret_cast<const float4*>(r1 + 192);

    float p0[4], p1[4];
    #pragma unroll
    for (int h = 0; h < 4; ++h) {
        const float4 w0 = *reinterpret_cast<const float4*>(&qWs[h][lq * 4]);
        const float4 w1 = *reinterpret_cast<const float4*>(&qWs[h][64 + lq * 4]);
        const float4 w2 = *reinterpret_cast<const float4*>(&qWs[h][128 + lq * 4]);
        const float4 w3 = *reinterpret_cast<const float4*>(&qWs[h][192 + lq * 4]);
        float s0 = 0.f, s1 = 0.f;
        s0 = dot4acc(e00, w0, s0); s0 = dot4acc(e01, w1, s0);
        s0 = dot4acc(e02, w2, s0); s0 = dot4acc(e03, w3, s0);
        s1 = dot4acc(e10, w0, s1); s1 = dot4acc(e11, w1, s1);
        s1 = dot4acc(e12, w2, s1); s1 = dot4acc(e13, w3, s1);
        p0[h] = s0; p1[h] = s1;
    }
    #pragma unroll
    for (int h = 0; h < 4; ++h) {
        p0[h] += __shfl_xor(p0[h], 1); p1[h] += __shfl_xor(p1[h], 1);
        p0[h] += __shfl_xor(p0[h], 2); p1[h] += __shfl_xor(p1[h], 2);
        p0[h] += __shfl_xor(p0[h], 4); p1[h] += __shfl_xor(p1[h], 4);
        p0[h] += __shfl_xor(p0[h], 8); p1[h] += __shfl_xor(p1[h], 8);
    }
    if (lq == 0) {
        #pragma unroll
        for (int h = 0; h < 4; ++h) {
            S_lds[h][w * 8 + lr]     = p0[h];
            S_lds[h][w * 8 + 4 + lr] = p1[h];
        }
    }
    __syncthreads();

    if (t < 128) {
        const int h = t >> 5, mi = t & 31;
        const size_t off = (size_t)((b * 4 + h) * 256 + n) * 256 + ms * 32 + mi;
        Sg[off] = (S_lds[h][mi] + Sqk[off]) * 0.125f;
    }
}

// ---------------------------------------------------------------------------
// S1b: per (bn): wave h reduces its score row -> (max, 1/sumexp)
// ---------------------------------------------------------------------------
__global__ __launch_bounds__(256) void softmax_stats(
    const float* __restrict__ Sg, float* __restrict__ MS)
{
    const int bn = blockIdx.x;
    const int b = bn >> 8, n = bn & 255;
    const int t = threadIdx.x;
    const int h = t >> 6, l = t & 63;
    const float* row = Sg + (size_t)((b * 4 + h) * 256 + n) * 256;
    const float4 s4 = *reinterpret_cast<const float4*>(&row[l * 4]);
    float mx = fmaxf(fmaxf(s4.x, s4.y), fmaxf(s4.z, s4.w));
    #pragma unroll
    for (int mask = 32; mask >= 1; mask >>= 1) mx = fmaxf(mx, __shfl_xor(mx, mask));
    float e = __expf(s4.x - mx) + __expf(s4.y - mx) + __expf(s4.z - mx) + __expf(s4.w - mx);
    #pragma unroll
    for (int mask = 32; mask >= 1; mask >>= 1) e += __shfl_xor(e, mask);
    if (l == 0) {
        const int idx = ((b * 4 + h) * 256 + n) * 2;
        MS[idx] = mx;
        MS[idx + 1] = 1.f / e;
    }
}

// ---------------------------------------------------------------------------
// S2: block (bn, ms in 0..7): attn = exp(S-mx)*inv (-> d_out), stream 32 rows
// of qv_emb with 8 loads upfront per wave, accumulate Ag[bn][ms][h][d].
// Wave w owns rows [w*8, w*8+8); lane owns d = l*4..l*4+3.
// ---------------------------------------------------------------------------
__global__ __launch_bounds__(256) void accum_kernel(
    const float* __restrict__ qv_emb, const float* __restrict__ Sg,
    const float* __restrict__ MS, float* __restrict__ attn_out,
    float* __restrict__ Ag)
{
    const int bn = blockIdx.x, ms = blockIdx.y;
    const int b = bn >> 8, n = bn & 255;
    const int t = threadIdx.x, w = t >> 6, l = t & 63;
    __shared__ float attn_lds[4][32];
    __shared__ float Apw[4][4][256];

    if (t < 128) {
        const int h = t >> 5, mi = t & 31;
        const size_t off = (size_t)((b * 4 + h) * 256 + n) * 256 + ms * 32 + mi;
        const int sidx = ((b * 4 + h) * 256 + n) * 2;
        const float a = __expf(Sg[off] - MS[sidx]) * MS[sidx + 1];
        attn_lds[h][mi] = a;
        attn_out[off] = a;
    }
    __syncthreads();

    // 8 independent row loads upfront (8 KB per wave in flight)
    const float* rb = qv_emb + (size_t)(bn * 256 + ms * 32 + w * 8) * 256 + l * 4;
    float4 e[8];
    #pragma unroll
    for (int rr = 0; rr < 8; ++rr)
        e[rr] = *reinterpret_cast<const float4*>(rb + rr * 256);

    float4 acc[4];
    #pragma unroll
    for (int h = 0; h < 4; ++h) acc[h] = make_float4(0.f, 0.f, 0.f, 0.f);

    #pragma unroll
    for (int rr = 0; rr < 8; ++rr) {
        #pragma unroll
        for (int h = 0; h < 4; ++h) {
            const float a = attn_lds[h][w * 8 + rr];
            acc[h].x = fmaf(a, e[rr].x, acc[h].x);
            acc[h].y = fmaf(a, e[rr].y, acc[h].y);
            acc[h].z = fmaf(a, e[rr].z, acc[h].z);
            acc[h].w = fmaf(a, e[rr].w, acc[h].w);
        }
    }
    #pragma unroll
    for (int h = 0; h < 4; ++h)
        *reinterpret_cast<float4*>(&Apw[w][h][l * 4]) = acc[h];
    __syncthreads();

    #pragma unroll
    for (int i = 0; i < 4; ++i) {
        const int idx = t + i * 256, h = idx >> 8, d = idx & 255;
        Ag[((size_t)(bn * 8 + ms) * 4 + h) * 256 + d] =
            Apw[0][h][d] + Apw[1][h][d] + Apw[2][h][d] + Apw[3][h][d];
    }
}

// ---------------------------------------------------------------------------
// S3: per (bn): hidden = attn@v + (sum_ms Ag)@Wqv + bqv
// ---------------------------------------------------------------------------
__global__ __launch_bounds__(256) void final_kernel(
    const float* __restrict__ qkvp, const float* __restrict__ Wqv,
    const float* __restrict__ bqv, const float* __restrict__ attn,
    const float* __restrict__ Ag, float* __restrict__ hidden)
{
    const int bn = blockIdx.x;
    const int b = bn >> 8, n = bn & 255;
    const int t = threadIdx.x;
    __shared__ float attn_s[4][256];
    __shared__ float Afull[4][256];

    {
        const int h = t >> 6, m4 = (t & 63) * 4;
        *reinterpret_cast<float4*>(&attn_s[h][m4]) =
            *reinterpret_cast<const float4*>(&attn[(size_t)((b * 4 + h) * 256 + n) * 256 + m4]);
    }
    #pragma unroll
    for (int i = 0; i < 4; ++i) {
        const int idx = t + i * 256, h = idx >> 8, d = idx & 255;
        float s = 0.f;
        #pragma unroll
        for (int msi = 0; msi < 8; ++msi)
            s += Ag[((size_t)(bn * 8 + msi) * 4 + h) * 256 + d];
        Afull[h][d] = s;
    }
    __syncthreads();

    const int c = t, h = c >> 6;
    float hv = bqv[c];
    const float* vcol = qkvp + (size_t)(1024 + b * 256) * 256 + c;
    #pragma unroll 8
    for (int m = 0; m < 256; ++m) hv = fmaf(attn_s[h][m], vcol[m * 256], hv);
    const float* wcol = Wqv + c;
    #pragma unroll 8
    for (int d = 0; d < 256; ++d) hv = fmaf(Afull[h][d], wcol[d * 256], hv);
    hidden[(size_t)bn * 256 + c] = hv;
}

extern "C" void kernel_launch(void* const* d_in, const int* in_sizes, int n_in,
                              void* d_out, int out_size, void* d_ws, size_t ws_size,
                              hipStream_t stream) {
    (void)in_sizes; (void)n_in; (void)out_size; (void)ws_size;
    const float* q_tok  = (const float*)d_in[0];
    const float* k_tok  = (const float*)d_in[1];
    const float* v_tok  = (const float*)d_in[2];
    const float* qk_emb = (const float*)d_in[3];
    const float* qv_emb = (const float*)d_in[4];
    const float* Wq  = (const float*)d_in[5];   const float* bq  = (const float*)d_in[6];
    const float* Wk  = (const float*)d_in[7];   const float* bk  = (const float*)d_in[8];
    const float* Wv  = (const float*)d_in[9];   const float* bv  = (const float*)d_in[10];
    const float* Wqk = (const float*)d_in[11];  /* bqk softmax-invariant */
    const float* Wqv = (const float*)d_in[13];  const float* bqv = (const float*)d_in[14];

    float* ws   = (float*)d_ws;
    float* qkvp = ws;                      // 1536*256   = 393216
    float* qW   = ws + 393216;             // 512*1024   = 524288
    float* Sqk  = ws + 917504;             // 2048*256   = 524288
    float* Sg   = ws + 1441792;            // 2048*256   = 524288
    float* MS   = ws + 1966080;            // 2048*2     = 4096
    float* Ag   = ws + 1970176;            // 512*8*4*256 = 4194304

    float* hidden = (float*)d_out;
    float* attn   = (float*)d_out + BB * NN * CC;

    proj_gemm    <<<dim3(24, 4),   256, 0, stream>>>(q_tok, k_tok, v_tok, Wq, bq, Wk, bk, Wv, bv, qkvp);
    qw_gemm      <<<dim3(8, 4, 4), 256, 0, stream>>>(qkvp, Wqk, qW);
    qk_gemm      <<<dim3(4, 4, 8), 256, 0, stream>>>(qkvp, Sqk);
    scores_kernel<<<dim3(512, 8),  256, 0, stream>>>(qk_emb, qW, Sqk, Sg);
    softmax_stats<<<512,           256, 0, stream>>>(Sg, MS);
    accum_kernel <<<dim3(512, 8),  256, 0, stream>>>(qv_emb, Sg, MS, attn, Ag);
    final_kernel <<<512,           256, 0, stream>>>(qkvp, Wqv, bqv, attn, Ag, hidden);
}